// Round 4
// baseline (596.165 us; speedup 1.0000x reference)
//
#include <hip/hip_runtime.h>
#include <hip/hip_bf16.h>
#include <stdint.h>

// R6: revert gemm_qk to R3 form (8-phase port regressed: K=512 too short to
// fill the pipeline, occupancy halved). NEW: fuse out-projection into the
// attention kernel (attn3, 8 waves = 8 heads = one bs-tile per block; block
// LDS O[32][520] -> each wave computes its 64-col slice of O @ W2t^T from
// L2-resident W2t). Eliminates gemm_bt<1> + the attn_out HBM round trip
// (134 MB). gemm_bt<0>/convert_x/prep + XCD swizzle (T1) unchanged.

typedef __attribute__((ext_vector_type(8))) short short8;
typedef __attribute__((ext_vector_type(4))) float f32x4;
typedef __attribute__((ext_vector_type(4))) unsigned int u32x4;

#define GPTR(p) ((const __attribute__((address_space(1))) void*)(p))
#define SPTR(p) ((__attribute__((address_space(3))) void*)(p))

__device__ __forceinline__ float b2f(unsigned short h) {
  union { unsigned u; float f; } c; c.u = ((unsigned)h) << 16; return c.f;
}
__device__ __forceinline__ unsigned short f2b(float f) {
  union { float f; unsigned u; } c; c.f = f;
  unsigned u = c.u;
  return (unsigned short)((u + 0x7fffu + ((u >> 16) & 1u)) >> 16);
}

// mask may arrive as int32[2] or byte-bool[2]; decode defensively.
__device__ __forceinline__ bool get_mask(const void* p, int b) {
  const unsigned* u = (const unsigned*)p;
  unsigned v0 = u[0], v1 = u[1];
  if (v0 <= 1u && v1 <= 1u) return (b ? v1 : v0) != 0u;
  const unsigned char* c = (const unsigned char*)p;
  return c[b] != 0;
}

// ---------------- prep: W1t[1536][512], W2t[512][512] (bf16), rope tables ----
__global__ __launch_bounds__(256) void prep(
    const float* __restrict__ wq, const float* __restrict__ wkv,
    const float* __restrict__ wout, const float* __restrict__ invf,
    unsigned short* __restrict__ W1t, unsigned short* __restrict__ W2t,
    float* __restrict__ cos_t, float* __restrict__ sin_t) {
  const int tid = blockIdx.x * 256 + threadIdx.x;
  if (tid < 1536 * 512) {
    const int j = tid >> 9, kk = tid & 511;
    // q scale 64^-0.5 = 0.125 folded into w_q (commutes with linear RoPE)
    float v = (j < 512) ? wq[kk * 512 + j] * 0.125f : wkv[kk * 1024 + (j - 512)];
    W1t[tid] = f2b(v);
  }
  if (tid < 512 * 512) {
    const int j = tid >> 9, kk = tid & 511;
    W2t[tid] = f2b(wout[kk * 512 + j]);
  }
  if (tid < 1024) {
    const int i = tid >> 5, p = tid & 31;
    const float f = (float)i * invf[p];
    cos_t[tid] = cosf(f);
    sin_t[tid] = sinf(f);
  }
}

// ---------------- convert x fp32 -> bf16 -------------------------------------
__global__ __launch_bounds__(256) void convert_x(const float* __restrict__ x,
                                                 unsigned short* __restrict__ xb) {
  const int i = (blockIdx.x * 256 + threadIdx.x) * 8;
  const float4 a = *(const float4*)(x + i);
  const float4 b = *(const float4*)(x + i + 4);
  union { unsigned short us[8]; u32x4 v; } o;
  o.us[0] = f2b(a.x); o.us[1] = f2b(a.y); o.us[2] = f2b(a.z); o.us[3] = f2b(a.w);
  o.us[4] = f2b(b.x); o.us[5] = f2b(b.y); o.us[6] = f2b(b.z); o.us[7] = f2b(b.w);
  *(u32x4*)(xb + i) = o.v;
}

// ---------------- generic GEMM: C = A[M][K] * Bt[N][K]^T  (m97 recipe) -------
// OUT_MODE 0: bf16 C^T to Cout[N][M] via LDS transpose (conflict-free b64 writes)
template <int OUT_MODE>
__global__ __launch_bounds__(256, 2) void gemm_bt(
    const unsigned short* __restrict__ A, const unsigned short* __restrict__ Bt,
    void* __restrict__ Cout, int M, int N, int K) {
  __shared__ __align__(16) unsigned short smem[17408];
  unsigned short* As = smem;
  unsigned short* Bs = smem + 8192;

  const int nb = N >> 7;
  const int cpx = gridDim.x >> 3;
  const int bid = (blockIdx.x & 7) * cpx + (blockIdx.x >> 3);
  const int bm = bid / nb, bn = bid % nb;
  const int t = threadIdx.x, lane = t & 63, w = t >> 6;
  const int wm = (w >> 1) << 6, wn = (w & 1) << 6;

  f32x4 acc[4][4] = {};

  const size_t Ks = (size_t)K;
  const unsigned short* gA = A + (size_t)(bm * 128 + w * 32 + (lane >> 3)) * Ks + ((lane & 7) << 3);
  const unsigned short* gB = Bt + (size_t)(bn * 128 + w * 32 + (lane >> 3)) * Ks + ((lane & 7) << 3);
  unsigned short* lA = As + w * 32 * 64;
  unsigned short* lB = Bs + w * 32 * 64;

  for (int k0 = 0; k0 < K; k0 += 64) {
#pragma unroll
    for (int i = 0; i < 4; ++i) {
      __builtin_amdgcn_global_load_lds(GPTR(gA + (size_t)i * 8 * Ks), SPTR(lA + i * 512), 16, 0, 0);
      __builtin_amdgcn_global_load_lds(GPTR(gB + (size_t)i * 8 * Ks), SPTR(lB + i * 512), 16, 0, 0);
    }
    gA += 64; gB += 64;
    __syncthreads();
#pragma unroll
    for (int ks = 0; ks < 2; ++ks) {
      const int kr = (ks << 5) + ((lane >> 4) << 3);
      const int r = lane & 15;
      short8 af[4], bf[4];
#pragma unroll
      for (int x = 0; x < 4; ++x) af[x] = *(const short8*)(As + (wm + (x << 4) + r) * 64 + kr);
#pragma unroll
      for (int x = 0; x < 4; ++x) bf[x] = *(const short8*)(Bs + (wn + (x << 4) + r) * 64 + kr);
#pragma unroll
      for (int xm = 0; xm < 4; ++xm)
#pragma unroll
        for (int xn = 0; xn < 4; ++xn)
          acc[xm][xn] = __builtin_amdgcn_mfma_f32_16x16x32_bf16(af[xm], bf[xn], acc[xm][xn], 0, 0, 0);
    }
    __syncthreads();
  }

  if (OUT_MODE == 0) {
    // C/D layout (16x16x32): col = lane&15, row = (lane>>4)*4 + reg [m89/m91]
    unsigned short* Ct = smem;  // [c:128][r stride 136]
    const int cb = wn + (lane & 15);
    const int rb = wm + ((lane >> 4) << 2);
#pragma unroll
    for (int xn = 0; xn < 4; ++xn)
#pragma unroll
      for (int xm = 0; xm < 4; ++xm) {
        const f32x4 v = acc[xm][xn];
        unsigned long long pk = (unsigned long long)f2b(v[0]) |
                                ((unsigned long long)f2b(v[1]) << 16) |
                                ((unsigned long long)f2b(v[2]) << 32) |
                                ((unsigned long long)f2b(v[3]) << 48);
        *(unsigned long long*)(Ct + (size_t)(cb + (xn << 4)) * 136 + rb + (xm << 4)) = pk;
      }
    __syncthreads();
    unsigned short* Cg = (unsigned short*)Cout;
#pragma unroll
    for (int it = 0; it < 8; ++it) {
      const int idx = it * 256 + t;
      const int c = idx >> 4;
      const int rc = (idx & 15) << 3;
      const u32x4 val = *(const u32x4*)(Ct + c * 136 + rc);
      *(u32x4*)(Cg + (size_t)(bn * 128 + c) * (size_t)M + (size_t)bm * 128 + rc) = val;
    }
  } else {
    float* Cg = (float*)Cout;
    const int cb = bn * 128 + wn + (lane & 15);
    const int rb = bm * 128 + wm + ((lane >> 4) << 2);
#pragma unroll
    for (int xm = 0; xm < 4; ++xm)
#pragma unroll
      for (int xn = 0; xn < 4; ++xn)
#pragma unroll
        for (int u = 0; u < 4; ++u)
          Cg[(size_t)(rb + (xm << 4) + u) * (size_t)N + cb + (xn << 4)] = acc[xm][xn][u];
  }
}

// ---------------- q/k GEMM: swapped-operand acc -> RoPE -> token-major out ---
__global__ __launch_bounds__(256, 2) void gemm_qk(
    const unsigned short* __restrict__ A, const unsigned short* __restrict__ Bt,
    unsigned short* __restrict__ qkout,
    const float* __restrict__ cos_t, const float* __restrict__ sin_t) {
  __shared__ __align__(16) unsigned short smem[17408];
  unsigned short* As = smem;
  unsigned short* Bs = smem + 8192;

  const int K = 512;
  const int bid = (blockIdx.x & 7) * 512 + (blockIdx.x >> 3);
  const int bm = bid >> 3, bn = bid & 7;
  const int t = threadIdx.x, lane = t & 63, w = t >> 6;
  const int wm = (w >> 1) << 6, wn = (w & 1) << 6;
  const int l15 = lane & 15, l4 = lane >> 4;

  f32x4 acc[4][4] = {};

  const size_t Ks = (size_t)K;
  const unsigned short* gA = A + (size_t)(bm * 128 + w * 32 + (lane >> 3)) * Ks + ((lane & 7) << 3);
  const unsigned short* gB = Bt + (size_t)(bn * 128 + w * 32 + (lane >> 3)) * Ks + ((lane & 7) << 3);
  unsigned short* lA = As + w * 32 * 64;
  unsigned short* lB = Bs + w * 32 * 64;

  for (int k0 = 0; k0 < K; k0 += 64) {
#pragma unroll
    for (int i = 0; i < 4; ++i) {
      __builtin_amdgcn_global_load_lds(GPTR(gA + (size_t)i * 8 * Ks), SPTR(lA + i * 512), 16, 0, 0);
      __builtin_amdgcn_global_load_lds(GPTR(gB + (size_t)i * 8 * Ks), SPTR(lB + i * 512), 16, 0, 0);
    }
    gA += 64; gB += 64;
    __syncthreads();
#pragma unroll
    for (int ks = 0; ks < 2; ++ks) {
      const int kr = (ks << 5) + (l4 << 3);
      short8 af[4], bf[4];
#pragma unroll
      for (int x = 0; x < 4; ++x) af[x] = *(const short8*)(As + (wm + (x << 4) + l15) * 64 + kr);
#pragma unroll
      for (int x = 0; x < 4; ++x) bf[x] = *(const short8*)(Bs + (wn + (x << 4) + l15) * 64 + kr);
#pragma unroll
      for (int xn = 0; xn < 4; ++xn)
#pragma unroll
        for (int xm = 0; xm < 4; ++xm)
          acc[xn][xm] = __builtin_amdgcn_mfma_f32_16x16x32_bf16(bf[xn], af[xm], acc[xn][xm], 0, 0, 0);
    }
    __syncthreads();
  }

  // Epilogue: RoPE in f32, pack bf16, LDS transpose to token-major.
  unsigned short* Ct = smem;  // [tok:128][n stride 136]
#pragma unroll
  for (int xn = 0; xn < 4; ++xn)
#pragma unroll
    for (int xm = 0; xm < 4; ++xm) {
      const int tloc = wm + (xm << 4) + l15;
      const int pos = tloc & 31;
      const int nloc = wn + (xn << 4) + (l4 << 2);
      const int p0 = ((bn * 128 + nloc) >> 1) & 31;
      const float c0 = cos_t[pos * 32 + p0], s0 = sin_t[pos * 32 + p0];
      const float c1 = cos_t[pos * 32 + p0 + 1], s1 = sin_t[pos * 32 + p0 + 1];
      const f32x4 v = acc[xn][xm];
      const float o0 = v[0] * c0 - v[1] * s0;
      const float o1 = v[1] * c0 + v[0] * s0;
      const float o2 = v[2] * c1 - v[3] * s1;
      const float o3 = v[3] * c1 + v[2] * s1;
      unsigned long long pk = (unsigned long long)f2b(o0) |
                              ((unsigned long long)f2b(o1) << 16) |
                              ((unsigned long long)f2b(o2) << 32) |
                              ((unsigned long long)f2b(o3) << 48);
      *(unsigned long long*)(Ct + (size_t)tloc * 136 + nloc) = pk;
    }
  __syncthreads();
#pragma unroll
  for (int it = 0; it < 8; ++it) {
    const int idx = it * 256 + t;
    const int tok = idx >> 4;
    const int c8 = (idx & 15) << 3;
    const u32x4 val = *(const u32x4*)(Ct + tok * 136 + c8);
    *(u32x4*)(qkout + (size_t)(bm * 128 + tok) * 1024 + bn * 128 + c8) = val;
  }
}

// ---------------- attention + fused out-projection ---------------------------
// One bs-tile per block, 8 waves = 8 heads. Attention identical to attn2 per
// wave; O tiles collected in block LDS [32][520] bf16; then each wave computes
// out[:, h*64 : h*64+64] = O @ W2t[h*64..][.]^T (128 MFMA) and stores f32.
__global__ __launch_bounds__(512, 4) void attn3(
    const unsigned short* __restrict__ qk,    // [65536][1024] bf16 (roped, q|k)
    const unsigned short* __restrict__ vbuf,  // [512][65536] bf16 feature-major
    const float* __restrict__ pos_bias,       // [8][32][32] f32
    const void* __restrict__ maskp,
    const unsigned short* __restrict__ W2t,   // [512][512] bf16 (wout^T)
    float* __restrict__ out) {                // [65536][512] f32
  const int h = threadIdx.x >> 6;  // wave = head
  const int lane = threadIdx.x & 63;
  const int bs = blockIdx.x;  // (b,hw) tile, 0..2047
  const int row0 = bs << 5;
  const int l15 = lane & 15, l4 = lane >> 4;

  __shared__ __align__(16) char lds[8 * 6656];  // 53248 B -> 3 blocks/CU
  char* wb = lds + h * 6656;
  float* S = (float*)wb;                              // [32][36] f32
  unsigned short* Pp = (unsigned short*)(wb + 4608);  // [2][64][8] frag-packed
  unsigned short* OldsB = (unsigned short*)lds;       // [32][520] bf16, block-level

  // ---- QK^T via mfma 16x16x32: frags straight from global -----------------
  const unsigned short* qb = qk + (size_t)row0 * 1024 + h * 64;
  short8 qf[2][2], kf[2][2];
#pragma unroll
  for (int ti = 0; ti < 2; ++ti)
#pragma unroll
    for (int ks = 0; ks < 2; ++ks) {
      const size_t off = (size_t)((ti << 4) + l15) * 1024 + (ks << 5) + (l4 << 3);
      qf[ti][ks] = *(const short8*)(qb + off);
      kf[ti][ks] = *(const short8*)(qb + 512 + off);
    }
  f32x4 sc[2][2];
#pragma unroll
  for (int ti = 0; ti < 2; ++ti)
#pragma unroll
    for (int tj = 0; tj < 2; ++tj) {
      f32x4 z = {0.f, 0.f, 0.f, 0.f};
      z = __builtin_amdgcn_mfma_f32_16x16x32_bf16(qf[ti][0], kf[tj][0], z, 0, 0, 0);
      sc[ti][tj] = __builtin_amdgcn_mfma_f32_16x16x32_bf16(qf[ti][1], kf[tj][1], z, 0, 0, 0);
    }
  // scatter S to LDS [i][j], stride 36
#pragma unroll
  for (int ti = 0; ti < 2; ++ti)
#pragma unroll
    for (int tj = 0; tj < 2; ++tj)
#pragma unroll
      for (int r = 0; r < 4; ++r)
        S[((ti << 4) + (l4 << 2) + r) * 36 + (tj << 4) + l15] = sc[ti][tj][r];
  __syncthreads();

  // ---- softmax: 2 lanes per row (halves), bias + focus-present mask --------
  {
    const int i = lane & 31;
    const int c = lane >> 5;
    const bool fm = get_mask(maskp, bs >> 10);
    float v[16];
    const float* Sr = S + i * 36 + (c << 4);
    const float* bp = pos_bias + h * 1024 + i * 32 + (c << 4);
#pragma unroll
    for (int g = 0; g < 4; ++g) {
      const float4 sv = *(const float4*)(Sr + (g << 2));
      const float4 bv = *(const float4*)(bp + (g << 2));
      v[g * 4 + 0] = sv.x + bv.x; v[g * 4 + 1] = sv.y + bv.y;
      v[g * 4 + 2] = sv.z + bv.z; v[g * 4 + 3] = sv.w + bv.w;
    }
    float m = v[0];
#pragma unroll
    for (int j = 1; j < 16; ++j) m = fmaxf(m, v[j]);
    m = fmaxf(m, __shfl_xor(m, 32, 64));
    float sum = 0.f;
#pragma unroll
    for (int j = 0; j < 16; ++j) { v[j] = __expf(v[j] - m); sum += v[j]; }
    sum += __shfl_xor(sum, 32, 64);
    const float inv = 1.f / sum;
    union { unsigned short us[8]; u32x4 u; } w0, w1;
    if (fm) {
#pragma unroll
      for (int j = 0; j < 8; ++j) {
        w0.us[j] = (((c << 4) + j) == i) ? (unsigned short)0x3F80 : (unsigned short)0;
        w1.us[j] = (((c << 4) + 8 + j) == i) ? (unsigned short)0x3F80 : (unsigned short)0;
      }
    } else {
#pragma unroll
      for (int j = 0; j < 8; ++j) {
        w0.us[j] = f2b(v[j] * inv);
        w1.us[j] = f2b(v[8 + j] * inv);
      }
    }
    const int ti = i >> 4, i15 = i & 15;
    *(u32x4*)(Pp + (size_t)((ti << 6) + ((2 * c + 0) << 4) + i15) * 8) = w0.u;
    *(u32x4*)(Pp + (size_t)((ti << 6) + ((2 * c + 1) << 4) + i15) * 8) = w1.u;
  }
  __syncthreads();

  // ---- PV: P frags from LDS (contiguous), V frags from global --------------
  short8 pf[2];
#pragma unroll
  for (int ti = 0; ti < 2; ++ti) pf[ti] = *(const short8*)(Pp + (size_t)((ti << 6) + lane) * 8);
  short8 vf[4];
#pragma unroll
  for (int td = 0; td < 4; ++td)
    vf[td] = *(const short8*)(vbuf + (size_t)(h * 64 + (td << 4) + l15) * 65536 + row0 + (l4 << 3));
  f32x4 o[2][4];
#pragma unroll
  for (int ti = 0; ti < 2; ++ti)
#pragma unroll
    for (int td = 0; td < 4; ++td) {
      f32x4 z = {0.f, 0.f, 0.f, 0.f};
      o[ti][td] = __builtin_amdgcn_mfma_f32_16x16x32_bf16(pf[ti], vf[td], z, 0, 0, 0);
    }
  __syncthreads();  // all waves done reading S/Pp before OldsB overwrites lds

  // ---- O -> block LDS bf16 [32][520] ---------------------------------------
#pragma unroll
  for (int ti = 0; ti < 2; ++ti)
#pragma unroll
    for (int td = 0; td < 4; ++td)
#pragma unroll
      for (int r = 0; r < 4; ++r)
        OldsB[((ti << 4) + (l4 << 2) + r) * 520 + (h << 6) + (td << 4) + l15] =
            f2b(o[ti][td][r]);
  __syncthreads();

  // ---- fused out-projection: out[32][h*64..+64] = O[32][512] @ W2t^T -------
  f32x4 pacc[2][4] = {};
  const unsigned short* Wp = W2t + (size_t)(h << 6) * 512;
#pragma unroll
  for (int ks = 0; ks < 16; ++ks) {
    const int kr = (ks << 5) + (l4 << 3);
    short8 af0 = *(const short8*)(OldsB + (size_t)l15 * 520 + kr);
    short8 af1 = *(const short8*)(OldsB + (size_t)(16 + l15) * 520 + kr);
    short8 bfr[4];
#pragma unroll
    for (int x = 0; x < 4; ++x)
      bfr[x] = *(const short8*)(Wp + (size_t)((x << 4) + l15) * 512 + kr);
#pragma unroll
    for (int n = 0; n < 4; ++n) {
      pacc[0][n] = __builtin_amdgcn_mfma_f32_16x16x32_bf16(af0, bfr[n], pacc[0][n], 0, 0, 0);
      pacc[1][n] = __builtin_amdgcn_mfma_f32_16x16x32_bf16(af1, bfr[n], pacc[1][n], 0, 0, 0);
    }
  }
  // C/D: col = lane&15 (n), row = (lane>>4)*4 + reg (m)  [same as gemm_bt]
  const int cb = (h << 6) + l15;
  const int rb = l4 << 2;
#pragma unroll
  for (int m = 0; m < 2; ++m)
#pragma unroll
    for (int n = 0; n < 4; ++n)
#pragma unroll
      for (int u = 0; u < 4; ++u)
        out[(size_t)(row0 + (m << 4) + rb + u) * 512 + cb + (n << 4)] = pacc[m][n][u];
}

// ---------------- launch ----------------------------------------------------
extern "C" void kernel_launch(void* const* d_in, const int* in_sizes, int n_in,
                              void* d_out, int out_size, void* d_ws, size_t ws_size,
                              hipStream_t stream) {
  const float* x = (const float*)d_in[0];
  const float* pos_bias = (const float*)d_in[1];
  const void* maskp = d_in[2];
  const float* wq = (const float*)d_in[3];
  const float* wkv = (const float*)d_in[4];
  const float* wout = (const float*)d_in[5];
  const float* invf = (const float*)d_in[6];

  char* ws = (char*)d_ws;
  unsigned short* xb = (unsigned short*)(ws);                // 67108864 B
  unsigned short* qkbuf = (unsigned short*)(ws + 67108864);  // 134217728 B [65536][1024]
  unsigned short* vbuf = (unsigned short*)(ws + 201326592);  // 67108864 B [512][65536]
  unsigned short* W1t = (unsigned short*)(ws + 268435456);   // 1572864 B
  unsigned short* W2t = (unsigned short*)(ws + 270008320);   // 524288 B
  float* cos_t = (float*)(ws + 270532608);                   // 4096 B
  float* sin_t = (float*)(ws + 270536704);                   // 4096 B

  prep<<<3072, 256, 0, stream>>>(wq, wkv, wout, invf, W1t, W2t, cos_t, sin_t);
  convert_x<<<16384, 256, 0, stream>>>(x, xb);
  gemm_qk<<<4096, 256, 0, stream>>>(xb, W1t, qkbuf, cos_t, sin_t);
  gemm_bt<0><<<2048, 256, 0, stream>>>(xb, W1t + (size_t)1024 * 512, (void*)vbuf, 65536, 512, 512);
  attn3<<<2048, 512, 0, stream>>>(qkbuf, vbuf, pos_bias, maskp, W2t, (float*)d_out);
}

// Round 5
// 537.869 us; speedup vs baseline: 1.1084x; 1.1084x over previous
//
#include <hip/hip_runtime.h>
#include <hip/hip_bf16.h>
#include <stdint.h>

// R7: revert attention to R4 config (attn2 + gemm_bt<1>; R6 fusion regressed:
// latency-bound 8-wave blocks). NEW: all three GEMMs get double-buffered LDS
// with ONE __syncthreads per K-iter (T3 minimum 2-phase): stage(i+1) issued
// AFTER the barrier, drained at the NEXT iter's barrier -> HBM latency hides
// under one compute phase instead of being fully exposed at vmcnt(0) drain.
// LDS 64 KB/block (2 x 32 KB stage), still 2 blocks/CU. T1 XCD swizzle kept.

typedef __attribute__((ext_vector_type(8))) short short8;
typedef __attribute__((ext_vector_type(4))) float f32x4;
typedef __attribute__((ext_vector_type(4))) unsigned int u32x4;

#define GPTR(p) ((const __attribute__((address_space(1))) void*)(p))
#define SPTR(p) ((__attribute__((address_space(3))) void*)(p))

__device__ __forceinline__ float b2f(unsigned short h) {
  union { unsigned u; float f; } c; c.u = ((unsigned)h) << 16; return c.f;
}
__device__ __forceinline__ unsigned short f2b(float f) {
  union { float f; unsigned u; } c; c.f = f;
  unsigned u = c.u;
  return (unsigned short)((u + 0x7fffu + ((u >> 16) & 1u)) >> 16);
}

// mask may arrive as int32[2] or byte-bool[2]; decode defensively.
__device__ __forceinline__ bool get_mask(const void* p, int b) {
  const unsigned* u = (const unsigned*)p;
  unsigned v0 = u[0], v1 = u[1];
  if (v0 <= 1u && v1 <= 1u) return (b ? v1 : v0) != 0u;
  const unsigned char* c = (const unsigned char*)p;
  return c[b] != 0;
}

// ---------------- prep: W1t[1536][512], W2t[512][512] (bf16), rope tables ----
__global__ __launch_bounds__(256) void prep(
    const float* __restrict__ wq, const float* __restrict__ wkv,
    const float* __restrict__ wout, const float* __restrict__ invf,
    unsigned short* __restrict__ W1t, unsigned short* __restrict__ W2t,
    float* __restrict__ cos_t, float* __restrict__ sin_t) {
  const int tid = blockIdx.x * 256 + threadIdx.x;
  if (tid < 1536 * 512) {
    const int j = tid >> 9, kk = tid & 511;
    // q scale 64^-0.5 = 0.125 folded into w_q (commutes with linear RoPE)
    float v = (j < 512) ? wq[kk * 512 + j] * 0.125f : wkv[kk * 1024 + (j - 512)];
    W1t[tid] = f2b(v);
  }
  if (tid < 512 * 512) {
    const int j = tid >> 9, kk = tid & 511;
    W2t[tid] = f2b(wout[kk * 512 + j]);
  }
  if (tid < 1024) {
    const int i = tid >> 5, p = tid & 31;
    const float f = (float)i * invf[p];
    cos_t[tid] = cosf(f);
    sin_t[tid] = sinf(f);
  }
}

// ---------------- convert x fp32 -> bf16 -------------------------------------
__global__ __launch_bounds__(256) void convert_x(const float* __restrict__ x,
                                                 unsigned short* __restrict__ xb) {
  const int i = (blockIdx.x * 256 + threadIdx.x) * 8;
  const float4 a = *(const float4*)(x + i);
  const float4 b = *(const float4*)(x + i + 4);
  union { unsigned short us[8]; u32x4 v; } o;
  o.us[0] = f2b(a.x); o.us[1] = f2b(a.y); o.us[2] = f2b(a.z); o.us[3] = f2b(a.w);
  o.us[4] = f2b(b.x); o.us[5] = f2b(b.y); o.us[6] = f2b(b.z); o.us[7] = f2b(b.w);
  *(u32x4*)(xb + i) = o.v;
}

// ---------------- generic GEMM: C = A[M][K] * Bt[N][K]^T  (dbuf 1-barrier) ---
// OUT_MODE 0: bf16 C^T to Cout[N][M] via LDS transpose
// OUT_MODE 1: fp32 row-major direct scatter to Cout[M][N]
template <int OUT_MODE>
__global__ __launch_bounds__(256, 2) void gemm_bt(
    const unsigned short* __restrict__ A, const unsigned short* __restrict__ Bt,
    void* __restrict__ Cout, int M, int N, int K) {
  // 2 x (As 8192 | Bs 8192) shorts = 65536 B; Ct epilogue reuses [0..17408)
  __shared__ __align__(16) unsigned short smem[32768];

  const int nb = N >> 7;
  const int cpx = gridDim.x >> 3;
  const int bid = (blockIdx.x & 7) * cpx + (blockIdx.x >> 3);
  const int bm = bid / nb, bn = bid % nb;
  const int t = threadIdx.x, lane = t & 63, w = t >> 6;
  const int wm = (w >> 1) << 6, wn = (w & 1) << 6;

  f32x4 acc[4][4] = {};

  const size_t Ks = (size_t)K;
  const unsigned short* gA = A + (size_t)(bm * 128 + w * 32 + (lane >> 3)) * Ks + ((lane & 7) << 3);
  const unsigned short* gB = Bt + (size_t)(bn * 128 + w * 32 + (lane >> 3)) * Ks + ((lane & 7) << 3);
  const int lofs = w * 32 * 64;

  const int kiter = K >> 6;
  // prologue: stage tile 0 into buf 0
#pragma unroll
  for (int i = 0; i < 4; ++i) {
    __builtin_amdgcn_global_load_lds(GPTR(gA + (size_t)i * 8 * Ks), SPTR(smem + lofs + i * 512), 16, 0, 0);
    __builtin_amdgcn_global_load_lds(GPTR(gB + (size_t)i * 8 * Ks), SPTR(smem + 8192 + lofs + i * 512), 16, 0, 0);
  }
  gA += 64; gB += 64;

  for (int it = 0; it < kiter; ++it) {
    __syncthreads();  // drains vmcnt(0): stage(it) landed for all waves
    if (it + 1 < kiter) {
      unsigned short* dst = smem + ((it + 1) & 1) * 16384;
#pragma unroll
      for (int i = 0; i < 4; ++i) {
        __builtin_amdgcn_global_load_lds(GPTR(gA + (size_t)i * 8 * Ks), SPTR(dst + lofs + i * 512), 16, 0, 0);
        __builtin_amdgcn_global_load_lds(GPTR(gB + (size_t)i * 8 * Ks), SPTR(dst + 8192 + lofs + i * 512), 16, 0, 0);
      }
      gA += 64; gB += 64;
    }
    const unsigned short* As = smem + (it & 1) * 16384;
    const unsigned short* Bs = As + 8192;
#pragma unroll
    for (int ks = 0; ks < 2; ++ks) {
      const int kr = (ks << 5) + ((lane >> 4) << 3);
      const int r = lane & 15;
      short8 af[4], bf[4];
#pragma unroll
      for (int x = 0; x < 4; ++x) af[x] = *(const short8*)(As + (wm + (x << 4) + r) * 64 + kr);
#pragma unroll
      for (int x = 0; x < 4; ++x) bf[x] = *(const short8*)(Bs + (wn + (x << 4) + r) * 64 + kr);
#pragma unroll
      for (int xm = 0; xm < 4; ++xm)
#pragma unroll
        for (int xn = 0; xn < 4; ++xn)
          acc[xm][xn] = __builtin_amdgcn_mfma_f32_16x16x32_bf16(af[xm], bf[xn], acc[xm][xn], 0, 0, 0);
    }
  }
  __syncthreads();  // all LDS reads done before epilogue overwrites smem

  if (OUT_MODE == 0) {
    // C/D layout (16x16x32): col = lane&15, row = (lane>>4)*4 + reg [m89/m91]
    unsigned short* Ct = smem;  // [c:128][r stride 136]
    const int cb = wn + (lane & 15);
    const int rb = wm + ((lane >> 4) << 2);
#pragma unroll
    for (int xn = 0; xn < 4; ++xn)
#pragma unroll
      for (int xm = 0; xm < 4; ++xm) {
        const f32x4 v = acc[xm][xn];
        unsigned long long pk = (unsigned long long)f2b(v[0]) |
                                ((unsigned long long)f2b(v[1]) << 16) |
                                ((unsigned long long)f2b(v[2]) << 32) |
                                ((unsigned long long)f2b(v[3]) << 48);
        *(unsigned long long*)(Ct + (size_t)(cb + (xn << 4)) * 136 + rb + (xm << 4)) = pk;
      }
    __syncthreads();
    unsigned short* Cg = (unsigned short*)Cout;
#pragma unroll
    for (int it = 0; it < 8; ++it) {
      const int idx = it * 256 + t;
      const int c = idx >> 4;
      const int rc = (idx & 15) << 3;
      const u32x4 val = *(const u32x4*)(Ct + c * 136 + rc);
      *(u32x4*)(Cg + (size_t)(bn * 128 + c) * (size_t)M + (size_t)bm * 128 + rc) = val;
    }
  } else {
    float* Cg = (float*)Cout;
    const int cb = bn * 128 + wn + (lane & 15);
    const int rb = bm * 128 + wm + ((lane >> 4) << 2);
#pragma unroll
    for (int xm = 0; xm < 4; ++xm)
#pragma unroll
      for (int xn = 0; xn < 4; ++xn)
#pragma unroll
        for (int u = 0; u < 4; ++u)
          Cg[(size_t)(rb + (xm << 4) + u) * (size_t)N + cb + (xn << 4)] = acc[xm][xn][u];
  }
}

// ---------------- q/k GEMM: dbuf + swapped-operand acc -> RoPE -> token-major
__global__ __launch_bounds__(256, 2) void gemm_qk(
    const unsigned short* __restrict__ A, const unsigned short* __restrict__ Bt,
    unsigned short* __restrict__ qkout,
    const float* __restrict__ cos_t, const float* __restrict__ sin_t) {
  __shared__ __align__(16) unsigned short smem[32768];  // dbuf; Ct reuses [0..17408)

  const int K = 512;
  const int bid = (blockIdx.x & 7) * 512 + (blockIdx.x >> 3);
  const int bm = bid >> 3, bn = bid & 7;
  const int t = threadIdx.x, lane = t & 63, w = t >> 6;
  const int wm = (w >> 1) << 6, wn = (w & 1) << 6;
  const int l15 = lane & 15, l4 = lane >> 4;

  f32x4 acc[4][4] = {};

  const size_t Ks = (size_t)K;
  const unsigned short* gA = A + (size_t)(bm * 128 + w * 32 + (lane >> 3)) * Ks + ((lane & 7) << 3);
  const unsigned short* gB = Bt + (size_t)(bn * 128 + w * 32 + (lane >> 3)) * Ks + ((lane & 7) << 3);
  const int lofs = w * 32 * 64;

  // prologue: stage tile 0 into buf 0
#pragma unroll
  for (int i = 0; i < 4; ++i) {
    __builtin_amdgcn_global_load_lds(GPTR(gA + (size_t)i * 8 * Ks), SPTR(smem + lofs + i * 512), 16, 0, 0);
    __builtin_amdgcn_global_load_lds(GPTR(gB + (size_t)i * 8 * Ks), SPTR(smem + 8192 + lofs + i * 512), 16, 0, 0);
  }
  gA += 64; gB += 64;

  for (int it = 0; it < 8; ++it) {
    __syncthreads();
    if (it + 1 < 8) {
      unsigned short* dst = smem + ((it + 1) & 1) * 16384;
#pragma unroll
      for (int i = 0; i < 4; ++i) {
        __builtin_amdgcn_global_load_lds(GPTR(gA + (size_t)i * 8 * Ks), SPTR(dst + lofs + i * 512), 16, 0, 0);
        __builtin_amdgcn_global_load_lds(GPTR(gB + (size_t)i * 8 * Ks), SPTR(dst + 8192 + lofs + i * 512), 16, 0, 0);
      }
      gA += 64; gB += 64;
    }
    const unsigned short* As = smem + (it & 1) * 16384;
    const unsigned short* Bs = As + 8192;
#pragma unroll
    for (int ks = 0; ks < 2; ++ks) {
      const int kr = (ks << 5) + (l4 << 3);
      short8 af[4], bf[4];
#pragma unroll
      for (int x = 0; x < 4; ++x) af[x] = *(const short8*)(As + (wm + (x << 4) + l15) * 64 + kr);
#pragma unroll
      for (int x = 0; x < 4; ++x) bf[x] = *(const short8*)(Bs + (wn + (x << 4) + l15) * 64 + kr);
#pragma unroll
      for (int xn = 0; xn < 4; ++xn)
#pragma unroll
        for (int xm = 0; xm < 4; ++xm)
          acc[xn][xm] = __builtin_amdgcn_mfma_f32_16x16x32_bf16(bf[xn], af[xm], acc[xn][xm], 0, 0, 0);
    }
  }
  __syncthreads();  // all LDS reads done before Ct overwrite

  // Epilogue: RoPE in f32, pack bf16, LDS transpose to token-major.
  unsigned short* Ct = smem;  // [tok:128][n stride 136]
#pragma unroll
  for (int xn = 0; xn < 4; ++xn)
#pragma unroll
    for (int xm = 0; xm < 4; ++xm) {
      const int tloc = wm + (xm << 4) + l15;
      const int pos = tloc & 31;  // bm*128 is 32-aligned
      const int nloc = wn + (xn << 4) + (l4 << 2);
      const int p0 = ((bn * 128 + nloc) >> 1) & 31;
      const float c0 = cos_t[pos * 32 + p0], s0 = sin_t[pos * 32 + p0];
      const float c1 = cos_t[pos * 32 + p0 + 1], s1 = sin_t[pos * 32 + p0 + 1];
      const f32x4 v = acc[xn][xm];
      const float o0 = v[0] * c0 - v[1] * s0;
      const float o1 = v[1] * c0 + v[0] * s0;
      const float o2 = v[2] * c1 - v[3] * s1;
      const float o3 = v[3] * c1 + v[2] * s1;
      unsigned long long pk = (unsigned long long)f2b(o0) |
                              ((unsigned long long)f2b(o1) << 16) |
                              ((unsigned long long)f2b(o2) << 32) |
                              ((unsigned long long)f2b(o3) << 48);
      *(unsigned long long*)(Ct + (size_t)tloc * 136 + nloc) = pk;
    }
  __syncthreads();
#pragma unroll
  for (int it = 0; it < 8; ++it) {
    const int idx = it * 256 + t;
    const int tok = idx >> 4;
    const int c8 = (idx & 15) << 3;
    const u32x4 val = *(const u32x4*)(Ct + tok * 136 + c8);
    *(u32x4*)(qkout + (size_t)(bm * 128 + tok) * 1024 + bn * 128 + c8) = val;
  }
}

// ---------------- attention: 1 wave per (bs,h), MFMA (verified R2/R4 form) ---
__global__ __launch_bounds__(256) void attn2(
    const unsigned short* __restrict__ qk,    // [65536][1024] bf16 (roped, q|k)
    const unsigned short* __restrict__ vbuf,  // [512][65536] bf16 feature-major
    const float* __restrict__ pos_bias,       // [8][32][32] f32
    const void* __restrict__ maskp,
    unsigned short* __restrict__ attn_out) {  // [65536][512] bf16 token-major
  const int wv = threadIdx.x >> 6;
  const int lane = threadIdx.x & 63;
  const int unit = blockIdx.x * 4 + wv;
  const int bs = unit >> 3, h = unit & 7;
  const int row0 = bs << 5;
  const int l15 = lane & 15, l4 = lane >> 4;

  __shared__ __align__(16) char lds[4 * 6656];
  char* wb = lds + wv * 6656;
  float* S = (float*)wb;                              // [32][36] f32
  unsigned short* Olds = (unsigned short*)wb;         // [32][72] bf16 (reuses S)
  unsigned short* Pp = (unsigned short*)(wb + 4608);  // [2][64][8] frag-packed

  const unsigned short* qb = qk + (size_t)row0 * 1024 + h * 64;
  short8 qf[2][2], kf[2][2];
#pragma unroll
  for (int ti = 0; ti < 2; ++ti)
#pragma unroll
    for (int ks = 0; ks < 2; ++ks) {
      const size_t off = (size_t)((ti << 4) + l15) * 1024 + (ks << 5) + (l4 << 3);
      qf[ti][ks] = *(const short8*)(qb + off);
      kf[ti][ks] = *(const short8*)(qb + 512 + off);
    }
  f32x4 sc[2][2];
#pragma unroll
  for (int ti = 0; ti < 2; ++ti)
#pragma unroll
    for (int tj = 0; tj < 2; ++tj) {
      f32x4 z = {0.f, 0.f, 0.f, 0.f};
      z = __builtin_amdgcn_mfma_f32_16x16x32_bf16(qf[ti][0], kf[tj][0], z, 0, 0, 0);
      sc[ti][tj] = __builtin_amdgcn_mfma_f32_16x16x32_bf16(qf[ti][1], kf[tj][1], z, 0, 0, 0);
    }
#pragma unroll
  for (int ti = 0; ti < 2; ++ti)
#pragma unroll
    for (int tj = 0; tj < 2; ++tj)
#pragma unroll
      for (int r = 0; r < 4; ++r)
        S[((ti << 4) + (l4 << 2) + r) * 36 + (tj << 4) + l15] = sc[ti][tj][r];
  __syncthreads();

  {
    const int i = lane & 31;
    const int c = lane >> 5;
    const bool fm = get_mask(maskp, bs >> 10);
    float v[16];
    const float* Sr = S + i * 36 + (c << 4);
    const float* bp = pos_bias + h * 1024 + i * 32 + (c << 4);
#pragma unroll
    for (int g = 0; g < 4; ++g) {
      const float4 sv = *(const float4*)(Sr + (g << 2));
      const float4 bv = *(const float4*)(bp + (g << 2));
      v[g * 4 + 0] = sv.x + bv.x; v[g * 4 + 1] = sv.y + bv.y;
      v[g * 4 + 2] = sv.z + bv.z; v[g * 4 + 3] = sv.w + bv.w;
    }
    float m = v[0];
#pragma unroll
    for (int j = 1; j < 16; ++j) m = fmaxf(m, v[j]);
    m = fmaxf(m, __shfl_xor(m, 32, 64));
    float sum = 0.f;
#pragma unroll
    for (int j = 0; j < 16; ++j) { v[j] = __expf(v[j] - m); sum += v[j]; }
    sum += __shfl_xor(sum, 32, 64);
    const float inv = 1.f / sum;
    union { unsigned short us[8]; u32x4 u; } w0, w1;
    if (fm) {
#pragma unroll
      for (int j = 0; j < 8; ++j) {
        w0.us[j] = (((c << 4) + j) == i) ? (unsigned short)0x3F80 : (unsigned short)0;
        w1.us[j] = (((c << 4) + 8 + j) == i) ? (unsigned short)0x3F80 : (unsigned short)0;
      }
    } else {
#pragma unroll
      for (int j = 0; j < 8; ++j) {
        w0.us[j] = f2b(v[j] * inv);
        w1.us[j] = f2b(v[8 + j] * inv);
      }
    }
    const int ti = i >> 4, i15 = i & 15;
    *(u32x4*)(Pp + (size_t)((ti << 6) + ((2 * c + 0) << 4) + i15) * 8) = w0.u;
    *(u32x4*)(Pp + (size_t)((ti << 6) + ((2 * c + 1) << 4) + i15) * 8) = w1.u;
  }
  __syncthreads();

  short8 pf[2];
#pragma unroll
  for (int ti = 0; ti < 2; ++ti) pf[ti] = *(const short8*)(Pp + (size_t)((ti << 6) + lane) * 8);
  short8 vf[4];
#pragma unroll
  for (int td = 0; td < 4; ++td)
    vf[td] = *(const short8*)(vbuf + (size_t)(h * 64 + (td << 4) + l15) * 65536 + row0 + (l4 << 3));
  f32x4 o[2][4];
#pragma unroll
  for (int ti = 0; ti < 2; ++ti)
#pragma unroll
    for (int td = 0; td < 4; ++td) {
      f32x4 z = {0.f, 0.f, 0.f, 0.f};
      o[ti][td] = __builtin_amdgcn_mfma_f32_16x16x32_bf16(pf[ti], vf[td], z, 0, 0, 0);
    }
  __syncthreads();

#pragma unroll
  for (int ti = 0; ti < 2; ++ti)
#pragma unroll
    for (int td = 0; td < 4; ++td)
#pragma unroll
      for (int r = 0; r < 4; ++r)
        Olds[((ti << 4) + (l4 << 2) + r) * 72 + (td << 4) + l15] = f2b(o[ti][td][r]);
  __syncthreads();
#pragma unroll
  for (int p = 0; p < 4; ++p) {
    const int idx = (p << 6) + lane;
    const int i = idx >> 3;
    const int ch = (idx & 7) << 3;
    const u32x4 val = *(const u32x4*)(Olds + i * 72 + ch);
    *(u32x4*)(attn_out + (size_t)(row0 + i) * 512 + h * 64 + ch) = val;
  }
}

// ---------------- launch ----------------------------------------------------
extern "C" void kernel_launch(void* const* d_in, const int* in_sizes, int n_in,
                              void* d_out, int out_size, void* d_ws, size_t ws_size,
                              hipStream_t stream) {
  const float* x = (const float*)d_in[0];
  const float* pos_bias = (const float*)d_in[1];
  const void* maskp = d_in[2];
  const float* wq = (const float*)d_in[3];
  const float* wkv = (const float*)d_in[4];
  const float* wout = (const float*)d_in[5];
  const float* invf = (const float*)d_in[6];

  char* ws = (char*)d_ws;
  unsigned short* xb = (unsigned short*)(ws);                // 67108864 B (reused as attn_out)
  unsigned short* qkbuf = (unsigned short*)(ws + 67108864);  // 134217728 B [65536][1024]
  unsigned short* vbuf = (unsigned short*)(ws + 201326592);  // 67108864 B [512][65536]
  unsigned short* W1t = (unsigned short*)(ws + 268435456);   // 1572864 B
  unsigned short* W2t = (unsigned short*)(ws + 270008320);   // 524288 B
  float* cos_t = (float*)(ws + 270532608);                   // 4096 B
  float* sin_t = (float*)(ws + 270536704);                   // 4096 B

  prep<<<3072, 256, 0, stream>>>(wq, wkv, wout, invf, W1t, W2t, cos_t, sin_t);
  convert_x<<<16384, 256, 0, stream>>>(x, xb);
  gemm_qk<<<4096, 256, 0, stream>>>(xb, W1t, qkbuf, cos_t, sin_t);
  gemm_bt<0><<<2048, 256, 0, stream>>>(xb, W1t + (size_t)1024 * 512, (void*)vbuf, 65536, 512, 512);
  attn2<<<4096, 256, 0, stream>>>(qkbuf, vbuf, pos_bias, maskp, xb);
  gemm_bt<1><<<2048, 256, 0, stream>>>(xb, W2t, d_out, 65536, 512, 512);
}

// Round 6
// 536.142 us; speedup vs baseline: 1.1120x; 1.0032x over previous
//
#include <hip/hip_runtime.h>
#include <hip/hip_bf16.h>
#include <stdint.h>

// R8: R7 + LDS XOR-swizzle (T2) on all three GEMMs. Diagnosis: 2.67e7 bank
// conflicts/dispatch = 12.8 extra cyc per ds_read_b128 (16-way conflict: row
// stride 128B = 32 banks). Per-CU LDS-unit time ~3200 cyc/K-iter matched the
// observed 3000 cyc/iter -> LDS-throughput-bound. Fix per rule 21 (both sides
// with global_load_lds): stage pre-swizzles GLOBAL src chunk
// ((lane&7)^((lane>>3)&7)), reads XOR chunk with row&7 (= lane&7). Each
// bank-quad now serves 8 lanes = b128 floor. dbuf + T1 swizzle kept.

typedef __attribute__((ext_vector_type(8))) short short8;
typedef __attribute__((ext_vector_type(4))) float f32x4;
typedef __attribute__((ext_vector_type(4))) unsigned int u32x4;

#define GPTR(p) ((const __attribute__((address_space(1))) void*)(p))
#define SPTR(p) ((__attribute__((address_space(3))) void*)(p))

__device__ __forceinline__ float b2f(unsigned short h) {
  union { unsigned u; float f; } c; c.u = ((unsigned)h) << 16; return c.f;
}
__device__ __forceinline__ unsigned short f2b(float f) {
  union { float f; unsigned u; } c; c.f = f;
  unsigned u = c.u;
  return (unsigned short)((u + 0x7fffu + ((u >> 16) & 1u)) >> 16);
}

// mask may arrive as int32[2] or byte-bool[2]; decode defensively.
__device__ __forceinline__ bool get_mask(const void* p, int b) {
  const unsigned* u = (const unsigned*)p;
  unsigned v0 = u[0], v1 = u[1];
  if (v0 <= 1u && v1 <= 1u) return (b ? v1 : v0) != 0u;
  const unsigned char* c = (const unsigned char*)p;
  return c[b] != 0;
}

// ---------------- prep: W1t[1536][512], W2t[512][512] (bf16), rope tables ----
__global__ __launch_bounds__(256) void prep(
    const float* __restrict__ wq, const float* __restrict__ wkv,
    const float* __restrict__ wout, const float* __restrict__ invf,
    unsigned short* __restrict__ W1t, unsigned short* __restrict__ W2t,
    float* __restrict__ cos_t, float* __restrict__ sin_t) {
  const int tid = blockIdx.x * 256 + threadIdx.x;
  if (tid < 1536 * 512) {
    const int j = tid >> 9, kk = tid & 511;
    // q scale 64^-0.5 = 0.125 folded into w_q (commutes with linear RoPE)
    float v = (j < 512) ? wq[kk * 512 + j] * 0.125f : wkv[kk * 1024 + (j - 512)];
    W1t[tid] = f2b(v);
  }
  if (tid < 512 * 512) {
    const int j = tid >> 9, kk = tid & 511;
    W2t[tid] = f2b(wout[kk * 512 + j]);
  }
  if (tid < 1024) {
    const int i = tid >> 5, p = tid & 31;
    const float f = (float)i * invf[p];
    cos_t[tid] = cosf(f);
    sin_t[tid] = sinf(f);
  }
}

// ---------------- convert x fp32 -> bf16 -------------------------------------
__global__ __launch_bounds__(256) void convert_x(const float* __restrict__ x,
                                                 unsigned short* __restrict__ xb) {
  const int i = (blockIdx.x * 256 + threadIdx.x) * 8;
  const float4 a = *(const float4*)(x + i);
  const float4 b = *(const float4*)(x + i + 4);
  union { unsigned short us[8]; u32x4 v; } o;
  o.us[0] = f2b(a.x); o.us[1] = f2b(a.y); o.us[2] = f2b(a.z); o.us[3] = f2b(a.w);
  o.us[4] = f2b(b.x); o.us[5] = f2b(b.y); o.us[6] = f2b(b.z); o.us[7] = f2b(b.w);
  *(u32x4*)(xb + i) = o.v;
}

// ---------------- generic GEMM: C = A[M][K] * Bt[N][K]^T  (dbuf + T2) --------
// LDS layout per 32x64 wave chunk: [row][chunk ^ (row&7)], chunk = 8-elem col
// group. Stage writes linearly; global src col pre-swizzled to compensate.
// OUT_MODE 0: bf16 C^T to Cout[N][M] via LDS transpose
// OUT_MODE 1: fp32 row-major direct scatter to Cout[M][N]
template <int OUT_MODE>
__global__ __launch_bounds__(256, 2) void gemm_bt(
    const unsigned short* __restrict__ A, const unsigned short* __restrict__ Bt,
    void* __restrict__ Cout, int M, int N, int K) {
  __shared__ __align__(16) unsigned short smem[32768];

  const int nb = N >> 7;
  const int cpx = gridDim.x >> 3;
  const int bid = (blockIdx.x & 7) * cpx + (blockIdx.x >> 3);
  const int bm = bid / nb, bn = bid % nb;
  const int t = threadIdx.x, lane = t & 63, w = t >> 6;
  const int wm = (w >> 1) << 6, wn = (w & 1) << 6;

  f32x4 acc[4][4] = {};

  const size_t Ks = (size_t)K;
  // T2 stage-side: LDS row = lane>>3 (mod 8) -> pre-swizzle global chunk
  const int scol = (((lane & 7) ^ ((lane >> 3) & 7)) << 3);
  const unsigned short* gA = A + (size_t)(bm * 128 + w * 32 + (lane >> 3)) * Ks + scol;
  const unsigned short* gB = Bt + (size_t)(bn * 128 + w * 32 + (lane >> 3)) * Ks + scol;
  const int lofs = w * 32 * 64;

  const int kiter = K >> 6;
#pragma unroll
  for (int i = 0; i < 4; ++i) {
    __builtin_amdgcn_global_load_lds(GPTR(gA + (size_t)i * 8 * Ks), SPTR(smem + lofs + i * 512), 16, 0, 0);
    __builtin_amdgcn_global_load_lds(GPTR(gB + (size_t)i * 8 * Ks), SPTR(smem + 8192 + lofs + i * 512), 16, 0, 0);
  }
  gA += 64; gB += 64;

  for (int it = 0; it < kiter; ++it) {
    __syncthreads();
    if (it + 1 < kiter) {
      unsigned short* dst = smem + ((it + 1) & 1) * 16384;
#pragma unroll
      for (int i = 0; i < 4; ++i) {
        __builtin_amdgcn_global_load_lds(GPTR(gA + (size_t)i * 8 * Ks), SPTR(dst + lofs + i * 512), 16, 0, 0);
        __builtin_amdgcn_global_load_lds(GPTR(gB + (size_t)i * 8 * Ks), SPTR(dst + 8192 + lofs + i * 512), 16, 0, 0);
      }
      gA += 64; gB += 64;
    }
    const unsigned short* As = smem + (it & 1) * 16384;
    const unsigned short* Bs = As + 8192;
#pragma unroll
    for (int ks = 0; ks < 2; ++ks) {
      // T2 read-side: chunk (ks*4 + l4) ^ (row&7); row&7 == lane&7 for all x
      const int cswz = ((((ks << 2) + (lane >> 4)) ^ (lane & 7)) << 3);
      const int r = lane & 15;
      short8 af[4], bf[4];
#pragma unroll
      for (int x = 0; x < 4; ++x) af[x] = *(const short8*)(As + (wm + (x << 4) + r) * 64 + cswz);
#pragma unroll
      for (int x = 0; x < 4; ++x) bf[x] = *(const short8*)(Bs + (wn + (x << 4) + r) * 64 + cswz);
#pragma unroll
      for (int xm = 0; xm < 4; ++xm)
#pragma unroll
        for (int xn = 0; xn < 4; ++xn)
          acc[xm][xn] = __builtin_amdgcn_mfma_f32_16x16x32_bf16(af[xm], bf[xn], acc[xm][xn], 0, 0, 0);
    }
  }
  __syncthreads();

  if (OUT_MODE == 0) {
    // C/D layout (16x16x32): col = lane&15, row = (lane>>4)*4 + reg [m89/m91]
    unsigned short* Ct = smem;  // [c:128][r stride 136]
    const int cb = wn + (lane & 15);
    const int rb = wm + ((lane >> 4) << 2);
#pragma unroll
    for (int xn = 0; xn < 4; ++xn)
#pragma unroll
      for (int xm = 0; xm < 4; ++xm) {
        const f32x4 v = acc[xm][xn];
        unsigned long long pk = (unsigned long long)f2b(v[0]) |
                                ((unsigned long long)f2b(v[1]) << 16) |
                                ((unsigned long long)f2b(v[2]) << 32) |
                                ((unsigned long long)f2b(v[3]) << 48);
        *(unsigned long long*)(Ct + (size_t)(cb + (xn << 4)) * 136 + rb + (xm << 4)) = pk;
      }
    __syncthreads();
    unsigned short* Cg = (unsigned short*)Cout;
#pragma unroll
    for (int it = 0; it < 8; ++it) {
      const int idx = it * 256 + t;
      const int c = idx >> 4;
      const int rc = (idx & 15) << 3;
      const u32x4 val = *(const u32x4*)(Ct + c * 136 + rc);
      *(u32x4*)(Cg + (size_t)(bn * 128 + c) * (size_t)M + (size_t)bm * 128 + rc) = val;
    }
  } else {
    float* Cg = (float*)Cout;
    const int cb = bn * 128 + wn + (lane & 15);
    const int rb = bm * 128 + wm + ((lane >> 4) << 2);
#pragma unroll
    for (int xm = 0; xm < 4; ++xm)
#pragma unroll
      for (int xn = 0; xn < 4; ++xn)
#pragma unroll
        for (int u = 0; u < 4; ++u)
          Cg[(size_t)(rb + (xm << 4) + u) * (size_t)N + cb + (xn << 4)] = acc[xm][xn][u];
  }
}

// ---------------- q/k GEMM: dbuf + T2 + swapped acc -> RoPE -> token-major ---
__global__ __launch_bounds__(256, 2) void gemm_qk(
    const unsigned short* __restrict__ A, const unsigned short* __restrict__ Bt,
    unsigned short* __restrict__ qkout,
    const float* __restrict__ cos_t, const float* __restrict__ sin_t) {
  __shared__ __align__(16) unsigned short smem[32768];

  const int K = 512;
  const int bid = (blockIdx.x & 7) * 512 + (blockIdx.x >> 3);
  const int bm = bid >> 3, bn = bid & 7;
  const int t = threadIdx.x, lane = t & 63, w = t >> 6;
  const int wm = (w >> 1) << 6, wn = (w & 1) << 6;
  const int l15 = lane & 15, l4 = lane >> 4;

  f32x4 acc[4][4] = {};

  const size_t Ks = (size_t)K;
  const int scol = (((lane & 7) ^ ((lane >> 3) & 7)) << 3);
  const unsigned short* gA = A + (size_t)(bm * 128 + w * 32 + (lane >> 3)) * Ks + scol;
  const unsigned short* gB = Bt + (size_t)(bn * 128 + w * 32 + (lane >> 3)) * Ks + scol;
  const int lofs = w * 32 * 64;

#pragma unroll
  for (int i = 0; i < 4; ++i) {
    __builtin_amdgcn_global_load_lds(GPTR(gA + (size_t)i * 8 * Ks), SPTR(smem + lofs + i * 512), 16, 0, 0);
    __builtin_amdgcn_global_load_lds(GPTR(gB + (size_t)i * 8 * Ks), SPTR(smem + 8192 + lofs + i * 512), 16, 0, 0);
  }
  gA += 64; gB += 64;

  for (int it = 0; it < 8; ++it) {
    __syncthreads();
    if (it + 1 < 8) {
      unsigned short* dst = smem + ((it + 1) & 1) * 16384;
#pragma unroll
      for (int i = 0; i < 4; ++i) {
        __builtin_amdgcn_global_load_lds(GPTR(gA + (size_t)i * 8 * Ks), SPTR(dst + lofs + i * 512), 16, 0, 0);
        __builtin_amdgcn_global_load_lds(GPTR(gB + (size_t)i * 8 * Ks), SPTR(dst + 8192 + lofs + i * 512), 16, 0, 0);
      }
      gA += 64; gB += 64;
    }
    const unsigned short* As = smem + (it & 1) * 16384;
    const unsigned short* Bs = As + 8192;
#pragma unroll
    for (int ks = 0; ks < 2; ++ks) {
      const int cswz = ((((ks << 2) + l4) ^ (lane & 7)) << 3);
      short8 af[4], bf[4];
#pragma unroll
      for (int x = 0; x < 4; ++x) af[x] = *(const short8*)(As + (wm + (x << 4) + l15) * 64 + cswz);
#pragma unroll
      for (int x = 0; x < 4; ++x) bf[x] = *(const short8*)(Bs + (wn + (x << 4) + l15) * 64 + cswz);
#pragma unroll
      for (int xn = 0; xn < 4; ++xn)
#pragma unroll
        for (int xm = 0; xm < 4; ++xm)
          acc[xn][xm] = __builtin_amdgcn_mfma_f32_16x16x32_bf16(bf[xn], af[xm], acc[xn][xm], 0, 0, 0);
    }
  }
  __syncthreads();

  // Epilogue: RoPE in f32, pack bf16, LDS transpose to token-major.
  unsigned short* Ct = smem;  // [tok:128][n stride 136]
#pragma unroll
  for (int xn = 0; xn < 4; ++xn)
#pragma unroll
    for (int xm = 0; xm < 4; ++xm) {
      const int tloc = wm + (xm << 4) + l15;
      const int pos = tloc & 31;  // bm*128 is 32-aligned
      const int nloc = wn + (xn << 4) + (l4 << 2);
      const int p0 = ((bn * 128 + nloc) >> 1) & 31;
      const float c0 = cos_t[pos * 32 + p0], s0 = sin_t[pos * 32 + p0];
      const float c1 = cos_t[pos * 32 + p0 + 1], s1 = sin_t[pos * 32 + p0 + 1];
      const f32x4 v = acc[xn][xm];
      const float o0 = v[0] * c0 - v[1] * s0;
      const float o1 = v[1] * c0 + v[0] * s0;
      const float o2 = v[2] * c1 - v[3] * s1;
      const float o3 = v[3] * c1 + v[2] * s1;
      unsigned long long pk = (unsigned long long)f2b(o0) |
                              ((unsigned long long)f2b(o1) << 16) |
                              ((unsigned long long)f2b(o2) << 32) |
                              ((unsigned long long)f2b(o3) << 48);
      *(unsigned long long*)(Ct + (size_t)tloc * 136 + nloc) = pk;
    }
  __syncthreads();
#pragma unroll
  for (int it = 0; it < 8; ++it) {
    const int idx = it * 256 + t;
    const int tok = idx >> 4;
    const int c8 = (idx & 15) << 3;
    const u32x4 val = *(const u32x4*)(Ct + tok * 136 + c8);
    *(u32x4*)(qkout + (size_t)(bm * 128 + tok) * 1024 + bn * 128 + c8) = val;
  }
}

// ---------------- attention: 1 wave per (bs,h), MFMA (verified R2/R4 form) ---
__global__ __launch_bounds__(256) void attn2(
    const unsigned short* __restrict__ qk,    // [65536][1024] bf16 (roped, q|k)
    const unsigned short* __restrict__ vbuf,  // [512][65536] bf16 feature-major
    const float* __restrict__ pos_bias,       // [8][32][32] f32
    const void* __restrict__ maskp,
    unsigned short* __restrict__ attn_out) {  // [65536][512] bf16 token-major
  const int wv = threadIdx.x >> 6;
  const int lane = threadIdx.x & 63;
  const int unit = blockIdx.x * 4 + wv;
  const int bs = unit >> 3, h = unit & 7;
  const int row0 = bs << 5;
  const int l15 = lane & 15, l4 = lane >> 4;

  __shared__ __align__(16) char lds[4 * 6656];
  char* wb = lds + wv * 6656;
  float* S = (float*)wb;                              // [32][36] f32
  unsigned short* Olds = (unsigned short*)wb;         // [32][72] bf16 (reuses S)
  unsigned short* Pp = (unsigned short*)(wb + 4608);  // [2][64][8] frag-packed

  const unsigned short* qb = qk + (size_t)row0 * 1024 + h * 64;
  short8 qf[2][2], kf[2][2];
#pragma unroll
  for (int ti = 0; ti < 2; ++ti)
#pragma unroll
    for (int ks = 0; ks < 2; ++ks) {
      const size_t off = (size_t)((ti << 4) + l15) * 1024 + (ks << 5) + (l4 << 3);
      qf[ti][ks] = *(const short8*)(qb + off);
      kf[ti][ks] = *(const short8*)(qb + 512 + off);
    }
  f32x4 sc[2][2];
#pragma unroll
  for (int ti = 0; ti < 2; ++ti)
#pragma unroll
    for (int tj = 0; tj < 2; ++tj) {
      f32x4 z = {0.f, 0.f, 0.f, 0.f};
      z = __builtin_amdgcn_mfma_f32_16x16x32_bf16(qf[ti][0], kf[tj][0], z, 0, 0, 0);
      sc[ti][tj] = __builtin_amdgcn_mfma_f32_16x16x32_bf16(qf[ti][1], kf[tj][1], z, 0, 0, 0);
    }
#pragma unroll
  for (int ti = 0; ti < 2; ++ti)
#pragma unroll
    for (int tj = 0; tj < 2; ++tj)
#pragma unroll
      for (int r = 0; r < 4; ++r)
        S[((ti << 4) + (l4 << 2) + r) * 36 + (tj << 4) + l15] = sc[ti][tj][r];
  __syncthreads();

  {
    const int i = lane & 31;
    const int c = lane >> 5;
    const bool fm = get_mask(maskp, bs >> 10);
    float v[16];
    const float* Sr = S + i * 36 + (c << 4);
    const float* bp = pos_bias + h * 1024 + i * 32 + (c << 4);
#pragma unroll
    for (int g = 0; g < 4; ++g) {
      const float4 sv = *(const float4*)(Sr + (g << 2));
      const float4 bv = *(const float4*)(bp + (g << 2));
      v[g * 4 + 0] = sv.x + bv.x; v[g * 4 + 1] = sv.y + bv.y;
      v[g * 4 + 2] = sv.z + bv.z; v[g * 4 + 3] = sv.w + bv.w;
    }
    float m = v[0];
#pragma unroll
    for (int j = 1; j < 16; ++j) m = fmaxf(m, v[j]);
    m = fmaxf(m, __shfl_xor(m, 32, 64));
    float sum = 0.f;
#pragma unroll
    for (int j = 0; j < 16; ++j) { v[j] = __expf(v[j] - m); sum += v[j]; }
    sum += __shfl_xor(sum, 32, 64);
    const float inv = 1.f / sum;
    union { unsigned short us[8]; u32x4 u; } w0, w1;
    if (fm) {
#pragma unroll
      for (int j = 0; j < 8; ++j) {
        w0.us[j] = (((c << 4) + j) == i) ? (unsigned short)0x3F80 : (unsigned short)0;
        w1.us[j] = (((c << 4) + 8 + j) == i) ? (unsigned short)0x3F80 : (unsigned short)0;
      }
    } else {
#pragma unroll
      for (int j = 0; j < 8; ++j) {
        w0.us[j] = f2b(v[j] * inv);
        w1.us[j] = f2b(v[8 + j] * inv);
      }
    }
    const int ti = i >> 4, i15 = i & 15;
    *(u32x4*)(Pp + (size_t)((ti << 6) + ((2 * c + 0) << 4) + i15) * 8) = w0.u;
    *(u32x4*)(Pp + (size_t)((ti << 6) + ((2 * c + 1) << 4) + i15) * 8) = w1.u;
  }
  __syncthreads();

  short8 pf[2];
#pragma unroll
  for (int ti = 0; ti < 2; ++ti) pf[ti] = *(const short8*)(Pp + (size_t)((ti << 6) + lane) * 8);
  short8 vf[4];
#pragma unroll
  for (int td = 0; td < 4; ++td)
    vf[td] = *(const short8*)(vbuf + (size_t)(h * 64 + (td << 4) + l15) * 65536 + row0 + (l4 << 3));
  f32x4 o[2][4];
#pragma unroll
  for (int ti = 0; ti < 2; ++ti)
#pragma unroll
    for (int td = 0; td < 4; ++td) {
      f32x4 z = {0.f, 0.f, 0.f, 0.f};
      o[ti][td] = __builtin_amdgcn_mfma_f32_16x16x32_bf16(pf[ti], vf[td], z, 0, 0, 0);
    }
  __syncthreads();

#pragma unroll
  for (int ti = 0; ti < 2; ++ti)
#pragma unroll
    for (int td = 0; td < 4; ++td)
#pragma unroll
      for (int r = 0; r < 4; ++r)
        Olds[((ti << 4) + (l4 << 2) + r) * 72 + (td << 4) + l15] = f2b(o[ti][td][r]);
  __syncthreads();
#pragma unroll
  for (int p = 0; p < 4; ++p) {
    const int idx = (p << 6) + lane;
    const int i = idx >> 3;
    const int ch = (idx & 7) << 3;
    const u32x4 val = *(const u32x4*)(Olds + i * 72 + ch);
    *(u32x4*)(attn_out + (size_t)(row0 + i) * 512 + h * 64 + ch) = val;
  }
}

// ---------------- launch ----------------------------------------------------
extern "C" void kernel_launch(void* const* d_in, const int* in_sizes, int n_in,
                              void* d_out, int out_size, void* d_ws, size_t ws_size,
                              hipStream_t stream) {
  const float* x = (const float*)d_in[0];
  const float* pos_bias = (const float*)d_in[1];
  const void* maskp = d_in[2];
  const float* wq = (const float*)d_in[3];
  const float* wkv = (const float*)d_in[4];
  const float* wout = (const float*)d_in[5];
  const float* invf = (const float*)d_in[6];

  char* ws = (char*)d_ws;
  unsigned short* xb = (unsigned short*)(ws);                // 67108864 B (reused as attn_out)
  unsigned short* qkbuf = (unsigned short*)(ws + 67108864);  // 134217728 B [65536][1024]
  unsigned short* vbuf = (unsigned short*)(ws + 201326592);  // 67108864 B [512][65536]
  unsigned short* W1t = (unsigned short*)(ws + 268435456);   // 1572864 B
  unsigned short* W2t = (unsigned short*)(ws + 270008320);   // 524288 B
  float* cos_t = (float*)(ws + 270532608);                   // 4096 B
  float* sin_t = (float*)(ws + 270536704);                   // 4096 B

  prep<<<3072, 256, 0, stream>>>(wq, wkv, wout, invf, W1t, W2t, cos_t, sin_t);
  convert_x<<<16384, 256, 0, stream>>>(x, xb);
  gemm_qk<<<4096, 256, 0, stream>>>(xb, W1t, qkbuf, cos_t, sin_t);
  gemm_bt<0><<<2048, 256, 0, stream>>>(xb, W1t + (size_t)1024 * 512, (void*)vbuf, 65536, 512, 512);
  attn2<<<4096, 256, 0, stream>>>(qkbuf, vbuf, pos_bias, maskp, xb);
  gemm_bt<1><<<2048, 256, 0, stream>>>(xb, W2t, d_out, 65536, 512, 512);
}